// Round 5
// baseline (354.566 us; speedup 1.0000x reference)
//
#include <hip/hip_runtime.h>
#include <hip/hip_bf16.h>

// Problem constants (B=4, T=2048, C=1024, H=16, HD=64)
#define BB 4
#define TT 2048
#define CC 1024
#define HH 16
#define HD 64

typedef _Float16 half8 __attribute__((ext_vector_type(8)));
typedef _Float16 half4 __attribute__((ext_vector_type(4)));
typedef _Float16 half2_t __attribute__((ext_vector_type(2)));
typedef float floatx4 __attribute__((ext_vector_type(4)));

// async global->LDS, 16B per lane (dest = wave-uniform base + lane*16)
__device__ __forceinline__ void async_cp16(const void* g, void* l) {
    __builtin_amdgcn_global_load_lds(
        (const __attribute__((address_space(1))) unsigned int*)g,
        (__attribute__((address_space(3))) unsigned int*)l,
        16, 0, 0);
}

// ---------------------------------------------------------------------------
// fp32 -> fp16 conversion, 8 elements/thread
// ---------------------------------------------------------------------------
__global__ void cvt_f32_f16(const float* __restrict__ src, _Float16* __restrict__ dst, int n) {
    int i = (blockIdx.x * blockDim.x + threadIdx.x) * 8;
    if (i < n) {
        float4 v0 = *(const float4*)(src + i);
        float4 v1 = *(const float4*)(src + i + 4);
        half8 h;
        h[0] = (_Float16)v0.x; h[1] = (_Float16)v0.y; h[2] = (_Float16)v0.z; h[3] = (_Float16)v0.w;
        h[4] = (_Float16)v1.x; h[5] = (_Float16)v1.y; h[6] = (_Float16)v1.z; h[7] = (_Float16)v1.w;
        *(half8*)(dst + i) = h;
    }
}

// ---------------------------------------------------------------------------
// NT GEMM, single-barrier LDS double-buffer: C[m][n] = sum_k A[m][k]*Bw[n][k]
// + bias[n]. 128x128 tile, BK=32 chunks, 256 thr (4 waves 2x2),
// global_load_lds width-16 prefetch one chunk ahead. mfma_f32_16x16x32_f16.
// EPI=0: scatter -> Q(scaled 0.125*log2e)/K/V fp16 [B*H, T, 64]
// EPI=1: fp32 -> c_out[m*N+n]
// ---------------------------------------------------------------------------
#define GEMM_CP(base, koffs)                                      \
    async_cp16(Ap0 + (koffs), (base) + tid * 8);                  \
    async_cp16(Ap1 + (koffs), (base) + 2048 + tid * 8);           \
    async_cp16(Bp0 + (koffs), (base) + 4096 + tid * 8);           \
    async_cp16(Bp1 + (koffs), (base) + 6144 + tid * 8);

#define GEMM_CHUNK(base)                                                        \
    {                                                                           \
        half8 af[4], bf[4];                                                     \
        _Pragma("unroll")                                                       \
        for (int mt = 0; mt < 4; mt++)                                          \
            af[mt] = *(const half8*)((base) + (wr * 64 + mt * 16 + lc) * 32 + quad * 8); \
        _Pragma("unroll")                                                       \
        for (int nt = 0; nt < 4; nt++)                                          \
            bf[nt] = *(const half8*)((base) + 4096 + (wc * 64 + nt * 16 + lc) * 32 + quad * 8); \
        _Pragma("unroll")                                                       \
        for (int mt = 0; mt < 4; mt++)                                          \
            _Pragma("unroll")                                                   \
            for (int nt = 0; nt < 4; nt++)                                      \
                acc[mt][nt] = __builtin_amdgcn_mfma_f32_16x16x32_f16(af[mt], bf[nt], acc[mt][nt], 0, 0, 0); \
    }

template <int EPI>
__global__ __launch_bounds__(256) void hgemm_nt(
    const _Float16* __restrict__ A, const _Float16* __restrict__ Bw,
    const float* __restrict__ bias,
    _Float16* __restrict__ q_out, _Float16* __restrict__ k_out, _Float16* __restrict__ v_out,
    float* __restrict__ c_out,
    int M, int N, int K)
{
    // buf layout: [buf][A 4096 | B 4096] halves; 2 bufs = 32 KB
    __shared__ __attribute__((aligned(16))) _Float16 Sb[2 * 8192];

    const int tid  = threadIdx.x;
    const int lane = tid & 63;
    const int wave = tid >> 6;
    const int quad = lane >> 4;
    const int lc   = lane & 15;
    const int wr   = wave >> 1, wc = wave & 1;
    const size_t bm = (size_t)blockIdx.y * 128;
    const size_t bn = (size_t)blockIdx.x * 128;

    const int r0 = tid >> 2;        // 0..63
    const int ck = (tid & 3) * 8;   // 0,8,16,24

    const _Float16* Ap0 = A + (bm + r0) * (size_t)K + ck;
    const _Float16* Ap1 = A + (bm + 64 + r0) * (size_t)K + ck;
    const _Float16* Bp0 = Bw + (bn + r0) * (size_t)K + ck;
    const _Float16* Bp1 = Bw + (bn + 64 + r0) * (size_t)K + ck;

    floatx4 acc[4][4] = {};

    GEMM_CP(Sb, 0);                       // prologue: chunk 0 -> buf0
    for (int kk = 0; kk < K; kk += 64) {
        __syncthreads();                  // buf0(kk) ready; buf1 free
        if (kk + 32 < K) { GEMM_CP(Sb + 8192, kk + 32); }
        GEMM_CHUNK(Sb);
        __syncthreads();                  // buf1(kk+32) ready; buf0 free
        if (kk + 64 < K) { GEMM_CP(Sb, kk + 64); }
        GEMM_CHUNK(Sb + 8192);
    }

#pragma unroll
    for (int mt = 0; mt < 4; mt++) {
        int mbase = (int)bm + wr * 64 + mt * 16 + quad * 4;
#pragma unroll
        for (int nt = 0; nt < 4; nt++) {
            int n = (int)bn + wc * 64 + nt * 16 + lc;
            float bv = bias[n];
#pragma unroll
            for (int r = 0; r < 4; r++) {
                float v = acc[mt][nt][r] + bv;
                int mm = mbase + r;
                if (EPI == 0) {
                    int seg = n >> 10;        // 0=Q 1=K 2=V
                    int cm  = n & 1023;
                    int h = cm >> 6, d = cm & 63;
                    int bb = mm >> 11, t = mm & 2047;
                    size_t dst = (((size_t)(bb * HH + h)) * TT + t) * HD + d;
                    // fold 1/sqrt(HD) * log2(e) into Q for exp2-based softmax
                    if (seg == 0)      q_out[dst] = (_Float16)(v * 0.18033688f);
                    else if (seg == 1) k_out[dst] = (_Float16)v;
                    else               v_out[dst] = (_Float16)v;
                } else {
                    c_out[(size_t)mm * N + n] = v;
                }
            }
        }
    }
}

// ---------------------------------------------------------------------------
// Flash attention, S^T formulation, 32 queries/wave, register prefetch of the
// next K/V tile issued at the top of the compute phase (latency hidden behind
// MFMA+softmax; drained by next iteration's first barrier).
// Grid (B*H, T/256), 512 thr = 8 waves. Key tile = 64.
// ---------------------------------------------------------------------------
__global__ __launch_bounds__(512) void attn_flash(
    const _Float16* __restrict__ Qp, const _Float16* __restrict__ Kp,
    const _Float16* __restrict__ Vp, _Float16* __restrict__ Op)
{
    __shared__ __attribute__((aligned(16))) _Float16 Ks[64][72];  // [key][dim]
    __shared__ __attribute__((aligned(16))) _Float16 Vt[64][76];  // [dim][key]

    const int bh   = blockIdx.x;   // 0..63 (b*16+h)
    const int qt   = blockIdx.y;   // 0..7
    const int tid  = threadIdx.x;
    const int lane = tid & 63;
    const int wave = tid >> 6;     // 0..7
    const int quad = lane >> 4;
    const int lc   = lane & 15;

    const size_t hb = (size_t)bh * TT * HD;
    const _Float16* Kh = Kp + hb;
    const _Float16* Vh = Vp + hb;

    // two query groups per wave; B-frag B[k=dim=quad*8+j][n=q=lc]
    const int q0row = qt * 256 + wave * 32 + lc;
    const int q1row = q0row + 16;
    half8 bq00 = *(const half8*)(Qp + hb + (size_t)q0row * HD + quad * 8);
    half8 bq01 = *(const half8*)(Qp + hb + (size_t)q0row * HD + 32 + quad * 8);
    half8 bq10 = *(const half8*)(Qp + hb + (size_t)q1row * HD + quad * 8);
    half8 bq11 = *(const half8*)(Qp + hb + (size_t)q1row * HD + 32 + quad * 8);

    floatx4 o0[4] = {}, o1[4] = {};  // O^T: dim = dt*16+quad*4+r, q = lc
    float m0 = -1e30f, l0 = 0.f, m1 = -1e30f, l1 = 0.f;

    // staging maps (512 threads)
    const int sk  = tid >> 3;          // K: key 0..63
    const int sc0 = (tid & 7) * 8;     // K: dim chunk
    const int vkp = tid >> 4;          // V: key pair 0..31
    const int vd4 = (tid & 15) * 4;    // V: dim group 0..60

    const _Float16* Kg  = Kh + (size_t)sk * HD + sc0;
    const _Float16* Vg0 = Vh + (size_t)(2 * vkp) * HD + vd4;
    const _Float16* Vg1 = Vg0 + HD;

    // prologue: tile 0 in registers
    half8 kv = *(const half8*)(Kg);
    half4 va = *(const half4*)(Vg0);
    half4 vb = *(const half4*)(Vg1);

    for (int kt = 0; kt < TT; kt += 64) {
        __syncthreads();  // prev tile fully consumed (also drains prefetch loads)
        *(half8*)&Ks[sk][sc0] = kv;
#pragma unroll
        for (int j = 0; j < 4; j++) {
            half2_t w; w[0] = va[j]; w[1] = vb[j];
            *(half2_t*)&Vt[vd4 + j][2 * vkp] = w;
        }
        __syncthreads();  // staging visible

        // prefetch next tile (wraps on last iter; latency hidden by compute)
        {
            size_t koff2 = (size_t)((kt + 64) & (TT - 1)) * HD;
            kv = *(const half8*)(Kg + koff2);
            va = *(const half4*)(Vg0 + koff2);
            vb = *(const half4*)(Vg1 + koff2);
        }

        // ---- S^T = K * Q^T : 4 keytiles x 2 dim-halves x 2 q-groups ----
        floatx4 s0[4], s1[4];
        const floatx4 zf = {0.f, 0.f, 0.f, 0.f};
#pragma unroll
        for (int m = 0; m < 4; m++) {
            half8 a0 = *(const half8*)&Ks[m * 16 + lc][quad * 8];
            half8 a1 = *(const half8*)&Ks[m * 16 + lc][32 + quad * 8];
            s0[m] = __builtin_amdgcn_mfma_f32_16x16x32_f16(a0, bq00, zf, 0, 0, 0);
            s0[m] = __builtin_amdgcn_mfma_f32_16x16x32_f16(a1, bq01, s0[m], 0, 0, 0);
            s1[m] = __builtin_amdgcn_mfma_f32_16x16x32_f16(a0, bq10, zf, 0, 0, 0);
            s1[m] = __builtin_amdgcn_mfma_f32_16x16x32_f16(a1, bq11, s1[m], 0, 0, 0);
        }

        // ---- online softmax per group (exp2; scale folded into Q) ----
        half4 pf0[4], pf1[4];
        {
            float mx = s0[0][0];
#pragma unroll
            for (int m = 0; m < 4; m++)
#pragma unroll
                for (int r = 0; r < 4; r++) mx = fmaxf(mx, s0[m][r]);
            mx = fmaxf(mx, __shfl_xor(mx, 16));
            mx = fmaxf(mx, __shfl_xor(mx, 32));
            float mnew = fmaxf(m0, mx);
            float al = exp2f(m0 - mnew);
            m0 = mnew;
            float rs = 0.f;
#pragma unroll
            for (int m = 0; m < 4; m++) {
                float p0 = exp2f(s0[m][0] - mnew);
                float p1 = exp2f(s0[m][1] - mnew);
                float p2 = exp2f(s0[m][2] - mnew);
                float p3 = exp2f(s0[m][3] - mnew);
                rs += (p0 + p1) + (p2 + p3);
                half4 t;
                t[0] = (_Float16)p0; t[1] = (_Float16)p1;
                t[2] = (_Float16)p2; t[3] = (_Float16)p3;
                pf0[m] = t;
            }
            rs += __shfl_xor(rs, 16);
            rs += __shfl_xor(rs, 32);
            l0 = l0 * al + rs;
#pragma unroll
            for (int dt = 0; dt < 4; dt++) o0[dt] *= al;
        }
        {
            float mx = s1[0][0];
#pragma unroll
            for (int m = 0; m < 4; m++)
#pragma unroll
                for (int r = 0; r < 4; r++) mx = fmaxf(mx, s1[m][r]);
            mx = fmaxf(mx, __shfl_xor(mx, 16));
            mx = fmaxf(mx, __shfl_xor(mx, 32));
            float mnew = fmaxf(m1, mx);
            float al = exp2f(m1 - mnew);
            m1 = mnew;
            float rs = 0.f;
#pragma unroll
            for (int m = 0; m < 4; m++) {
                float p0 = exp2f(s1[m][0] - mnew);
                float p1 = exp2f(s1[m][1] - mnew);
                float p2 = exp2f(s1[m][2] - mnew);
                float p3 = exp2f(s1[m][3] - mnew);
                rs += (p0 + p1) + (p2 + p3);
                half4 t;
                t[0] = (_Float16)p0; t[1] = (_Float16)p1;
                t[2] = (_Float16)p2; t[3] = (_Float16)p3;
                pf1[m] = t;
            }
            rs += __shfl_xor(rs, 16);
            rs += __shfl_xor(rs, 32);
            l1 = l1 * al + rs;
#pragma unroll
            for (int dt = 0; dt < 4; dt++) o1[dt] *= al;
        }

        // ---- O^T += V^T * P^T : V-frags shared across both q-groups ----
#pragma unroll
        for (int dt = 0; dt < 4; dt++) {
            const _Float16* vr = &Vt[dt * 16 + lc][quad * 4];
#pragma unroll
            for (int m = 0; m < 4; m++) {
                half4 vfr = *(const half4*)(vr + m * 16);  // keys m*16+quad*4+{0..3}
                o0[dt] = __builtin_amdgcn_mfma_f32_16x16x16f16(vfr, pf0[m], o0[dt], 0, 0, 0);
                o1[dt] = __builtin_amdgcn_mfma_f32_16x16x16f16(vfr, pf1[m], o1[dt], 0, 0, 0);
            }
        }
    }

    // epilogue: O^T reg (dt, r) -> dim = dt*16 + quad*4 + r, t = q{0,1}row
    const int b = bh >> 4, h = bh & 15;
    {
        float inv = 1.0f / l0;
        size_t base = ((size_t)(b * TT + q0row)) * CC + h * HD;
#pragma unroll
        for (int dt = 0; dt < 4; dt++) {
            half4 hv;
#pragma unroll
            for (int r = 0; r < 4; r++) hv[r] = (_Float16)(o0[dt][r] * inv);
            *(half4*)(Op + base + dt * 16 + quad * 4) = hv;
        }
    }
    {
        float inv = 1.0f / l1;
        size_t base = ((size_t)(b * TT + q1row)) * CC + h * HD;
#pragma unroll
        for (int dt = 0; dt < 4; dt++) {
            half4 hv;
#pragma unroll
            for (int r = 0; r < 4; r++) hv[r] = (_Float16)(o1[dt][r] * inv);
            *(half4*)(Op + base + dt * 16 + quad * 4) = hv;
        }
    }
}

// ---------------------------------------------------------------------------
extern "C" void kernel_launch(void* const* d_in, const int* in_sizes, int n_in,
                              void* d_out, int out_size, void* d_ws, size_t ws_size,
                              hipStream_t stream) {
    const float* x      = (const float*)d_in[0];  // [B,T,C]
    const float* W_attn = (const float*)d_in[1];  // [3C,C]
    const float* b_attn = (const float*)d_in[2];  // [3C]
    const float* W_proj = (const float*)d_in[3];  // [C,C]
    const float* b_proj = (const float*)d_in[4];  // [C]
    float* out = (float*)d_out;

    const size_t SZ_XH  = (size_t)BB * TT * CC * 2;
    const size_t SZ_WA  = (size_t)3 * CC * CC * 2;
    const size_t SZ_WP  = (size_t)CC * CC * 2;
    const size_t SZ_QKV = (size_t)BB * HH * TT * HD * 2;
    size_t off = 0;
    _Float16* xh  = (_Float16*)((char*)d_ws + off); off += SZ_XH;
    _Float16* wah = (_Float16*)((char*)d_ws + off); off += SZ_WA;
    _Float16* wph = (_Float16*)((char*)d_ws + off); off += SZ_WP;
    _Float16* Qh  = (_Float16*)((char*)d_ws + off); off += SZ_QKV;
    _Float16* Kh  = (_Float16*)((char*)d_ws + off); off += SZ_QKV;
    _Float16* Vh  = (_Float16*)((char*)d_ws + off); off += SZ_QKV;
    _Float16* Ah  = (_Float16*)((char*)d_ws + off); off += SZ_XH;
    if (ws_size < off) return;

    const int NX  = BB * TT * CC;
    const int NWA = 3 * CC * CC;
    const int NWP = CC * CC;
    cvt_f32_f16<<<NX / 8 / 256, 256, 0, stream>>>(x, xh, NX);
    cvt_f32_f16<<<NWA / 8 / 256, 256, 0, stream>>>(W_attn, wah, NWA);
    cvt_f32_f16<<<NWP / 8 / 256, 256, 0, stream>>>(W_proj, wph, NWP);

    hgemm_nt<0><<<dim3(3 * CC / 128, BB * TT / 128), 256, 0, stream>>>(
        xh, wah, b_attn, Qh, Kh, Vh, nullptr, BB * TT, 3 * CC, CC);

    attn_flash<<<dim3(BB * HH, TT / 256), 512, 0, stream>>>(Qh, Kh, Vh, Ah);

    hgemm_nt<1><<<dim3(CC / 128, BB * TT / 128), 256, 0, stream>>>(
        Ah, wph, b_proj, nullptr, nullptr, nullptr, out, BB * TT, CC, CC);
}